// Round 1
// baseline (933.249 us; speedup 1.0000x reference)
//
#include <hip/hip_runtime.h>
#include <hip/hip_bf16.h>

typedef __bf16 bf16;
typedef __bf16 bf16x4 __attribute__((ext_vector_type(4)));
typedef __bf16 bf16x8 __attribute__((ext_vector_type(8)));
typedef float  f32x4  __attribute__((ext_vector_type(4)));

#define EDIM 1536
#define DDIM 128
#define CDIM 1664   // E + D
#define TM   64
#define NSTG 24     // 1536 / 64

#define MFMA_B16(a, b, c) __builtin_amdgcn_mfma_f32_16x16x32_bf16((a), (b), (c), 0, 0, 0)

__device__ __forceinline__ float sigf(float x) { return 1.0f / (1.0f + __expf(-x)); }
__device__ __forceinline__ float tanhf_fast(float x) { return 2.0f / (1.0f + __expf(-2.0f * x)) - 1.0f; }

// f32 -> bf16 weight conversion into workspace
__global__ __launch_bounds__(256) void prep_convert(const float* __restrict__ w_ih,
                                                    const float* __restrict__ w_hh,
                                                    bf16* __restrict__ wib,
                                                    bf16* __restrict__ whb) {
  const int i = (blockIdx.x * 256 + threadIdx.x) * 4;
  const int TIH = 3 * DDIM * EDIM;   // 589824
  const int THH = 3 * DDIM * DDIM;   // 49152
  if (i < TIH) {
    const float4 v = *(const float4*)(w_ih + i);
    bf16x4 o = {(bf16)v.x, (bf16)v.y, (bf16)v.z, (bf16)v.w};
    *(bf16x4*)(wib + i) = o;
  } else if (i < TIH + THH) {
    const int j = i - TIH;
    const float4 v = *(const float4*)(w_hh + j);
    bf16x4 o = {(bf16)v.x, (bf16)v.y, (bf16)v.z, (bf16)v.w};
    *(bf16x4*)(whb + j) = o;
  }
}

// Fused: gi = emb@w_ih^T + b_ih ; gh = mem[ids]@w_hh^T + b_hh ; GRU gates ;
// scatter new_mem ; logits = [emb;new_mem]@cls_w^T + cls_b.
// Block: TM=64 rows, 512 thr = 8 waves, wave (wm,wn): rows [32*wm,+32),
// gate-aligned cols d in [32*wn,+32) of each of the 3 gates.
__global__ __launch_bounds__(512, 2) void gru_fused(
    const float* __restrict__ emb, const int* __restrict__ ids,
    const float* __restrict__ mem,
    const float* __restrict__ b_ih, const float* __restrict__ b_hh,
    const float* __restrict__ cls_w, const float* __restrict__ cls_b,
    const bf16* __restrict__ wib, const bf16* __restrict__ whb,
    float* __restrict__ logits, float* __restrict__ omem, int Nrows)
{
  __shared__ bf16  sBuf[8192];   // phase A: 2 x [64][64] dbuf ; phase B: [64][128]
  __shared__ float sLp[64][2];
  __shared__ int   sIds[64];

  const int t    = threadIdx.x;
  const int lane = t & 63;
  const int wave = t >> 6;
  const int wm   = wave >> 2;     // 0..1
  const int wn   = wave & 3;      // 0..3
  const int l15  = lane & 15;
  const int lq   = lane >> 4;     // 0..3
  const int m0   = blockIdx.x * TM;

  if (t < 64)  sIds[t] = (m0 + t < Nrows) ? ids[m0 + t] : 0;
  if (t < 128) sLp[t >> 1][t & 1] = cls_b[t & 1];

  // accumulators, bias-initialized (r,z get b_ih+b_hh; n-gate split: accN=b_ih, accH=b_hh)
  f32x4 accR[2][2], accZ[2][2], accN[2][2], accH[2][2];
#pragma unroll
  for (int sub = 0; sub < 2; ++sub) {
    const int nc = wn * 32 + sub * 16 + l15;
    const float br = b_ih[nc] + b_hh[nc];
    const float bz = b_ih[128 + nc] + b_hh[128 + nc];
    const float bn = b_ih[256 + nc];
    const float bh = b_hh[256 + nc];
#pragma unroll
    for (int mt = 0; mt < 2; ++mt) {
      accR[mt][sub] = (f32x4){br, br, br, br};
      accZ[mt][sub] = (f32x4){bz, bz, bz, bz};
      accN[mt][sub] = (f32x4){bn, bn, bn, bn};
      accH[mt][sub] = (f32x4){bh, bh, bh, bh};
    }
  }

  // ---------------- Phase A: gi over K=1536, BK=64, LDS double-buffered ----------------
  const int srow = t >> 4;            // 0..31 (staging row group)
  const int scol = (t & 15) << 2;     // f32 col within 64-wide k-slice
  const bool v0 = (m0 + srow) < Nrows;
  const bool v1 = (m0 + 32 + srow) < Nrows;
  const float* pA0 = emb + (size_t)(m0 + srow) * EDIM + scol;
  const float* pA1 = emb + (size_t)(m0 + 32 + srow) * EDIM + scol;
  const int wb0 = srow * 128        + ((scol << 1) ^ ((srow & 7) << 4));
  const int wb1 = (32 + srow) * 128 + ((scol << 1) ^ ((srow & 7) << 4));
  char* sB0 = (char*)sBuf;
  char* sB1 = (char*)(sBuf + 4096);

  float lpA[2][2] = {{0.f, 0.f}, {0.f, 0.f}};

  { // prologue: stage k-slice 0 into buffer 0
    float4 a0 = make_float4(0.f, 0.f, 0.f, 0.f), a1 = a0;
    if (v0) a0 = *(const float4*)(pA0);
    if (v1) a1 = *(const float4*)(pA1);
    const float4 c0 = *(const float4*)(cls_w + scol);
    const float4 c1 = *(const float4*)(cls_w + CDIM + scol);
    lpA[0][0] += a0.x * c0.x + a0.y * c0.y + a0.z * c0.z + a0.w * c0.w;
    lpA[0][1] += a0.x * c1.x + a0.y * c1.y + a0.z * c1.z + a0.w * c1.w;
    lpA[1][0] += a1.x * c0.x + a1.y * c0.y + a1.z * c0.z + a1.w * c0.w;
    lpA[1][1] += a1.x * c1.x + a1.y * c1.y + a1.z * c1.z + a1.w * c1.w;
    bf16x4 o0 = {(bf16)a0.x, (bf16)a0.y, (bf16)a0.z, (bf16)a0.w};
    bf16x4 o1 = {(bf16)a1.x, (bf16)a1.y, (bf16)a1.z, (bf16)a1.w};
    *(bf16x4*)(sB0 + wb0) = o0;
    *(bf16x4*)(sB0 + wb1) = o1;
  }
  __syncthreads();

  for (int s = 0; s < NSTG; ++s) {
    char* cur = (s & 1) ? sB1 : sB0;
    char* nxt = (s & 1) ? sB0 : sB1;
    const int k0 = s * 64;
    const bool pf = (s + 1) < NSTG;
    float4 a0 = make_float4(0.f, 0.f, 0.f, 0.f), a1 = a0, c0 = a0, c1 = a0;
    if (pf) { // issue next-slice loads early (overlap with MFMA below)
      const int kn = k0 + 64;
      if (v0) a0 = *(const float4*)(pA0 + kn);
      if (v1) a1 = *(const float4*)(pA1 + kn);
      c0 = *(const float4*)(cls_w + kn + scol);
      c1 = *(const float4*)(cls_w + CDIM + kn + scol);
    }
#pragma unroll
    for (int ks = 0; ks < 2; ++ks) {
      bf16x8 af[2];
#pragma unroll
      for (int mt = 0; mt < 2; ++mt) {
        const int m = wm * 32 + mt * 16 + l15;
        const int kb = (ks * 32 + lq * 8) << 1;
        af[mt] = *(bf16x8*)(cur + m * 128 + (kb ^ ((m & 7) << 4)));
      }
      const int kg = k0 + ks * 32 + lq * 8;
#pragma unroll
      for (int g = 0; g < 3; ++g) {
#pragma unroll
        for (int sub = 0; sub < 2; ++sub) {
          const int n = g * 128 + wn * 32 + sub * 16 + l15;
          const bf16x8 bfr = *(const bf16x8*)(wib + (size_t)n * EDIM + kg);
          if (g == 0) {
            accR[0][sub] = MFMA_B16(af[0], bfr, accR[0][sub]);
            accR[1][sub] = MFMA_B16(af[1], bfr, accR[1][sub]);
          } else if (g == 1) {
            accZ[0][sub] = MFMA_B16(af[0], bfr, accZ[0][sub]);
            accZ[1][sub] = MFMA_B16(af[1], bfr, accZ[1][sub]);
          } else {
            accN[0][sub] = MFMA_B16(af[0], bfr, accN[0][sub]);
            accN[1][sub] = MFMA_B16(af[1], bfr, accN[1][sub]);
          }
        }
      }
    }
    if (pf) {
      lpA[0][0] += a0.x * c0.x + a0.y * c0.y + a0.z * c0.z + a0.w * c0.w;
      lpA[0][1] += a0.x * c1.x + a0.y * c1.y + a0.z * c1.z + a0.w * c1.w;
      lpA[1][0] += a1.x * c0.x + a1.y * c0.y + a1.z * c0.z + a1.w * c0.w;
      lpA[1][1] += a1.x * c1.x + a1.y * c1.y + a1.z * c1.z + a1.w * c1.w;
      bf16x4 o0 = {(bf16)a0.x, (bf16)a0.y, (bf16)a0.z, (bf16)a0.w};
      bf16x4 o1 = {(bf16)a1.x, (bf16)a1.y, (bf16)a1.z, (bf16)a1.w};
      *(bf16x4*)(nxt + wb0) = o0;
      *(bf16x4*)(nxt + wb1) = o1;
    }
    __syncthreads();
  }

  // classifier emb-part: reduce over the 16 threads sharing each row -> LDS
#pragma unroll
  for (int p = 0; p < 2; ++p) {
#pragma unroll
    for (int c = 0; c < 2; ++c) {
      float v = lpA[p][c];
      v += __shfl_xor(v, 1); v += __shfl_xor(v, 2);
      v += __shfl_xor(v, 4); v += __shfl_xor(v, 8);
      if (l15 == 0) atomicAdd(&sLp[p * 32 + srow][c], v);
    }
  }

  // ---------------- Phase B: gh over K=128, prev gathered by ids ----------------
  {
    const int prow = t >> 5;            // 0..15
    const int pcol = (t & 31) << 2;     // 0..124
#pragma unroll
    for (int p = 0; p < 4; ++p) {
      const int r = p * 16 + prow;
      const float4 v = *(const float4*)(mem + (size_t)sIds[r] * DDIM + pcol);
      bf16x4 o = {(bf16)v.x, (bf16)v.y, (bf16)v.z, (bf16)v.w};
      *(bf16x4*)((char*)sBuf + r * 256 + ((pcol << 1) ^ ((r & 7) << 4))) = o;
    }
  }
  __syncthreads();

#pragma unroll
  for (int ks = 0; ks < 4; ++ks) {
    bf16x8 af[2];
#pragma unroll
    for (int mt = 0; mt < 2; ++mt) {
      const int m = wm * 32 + mt * 16 + l15;
      const int kb = (ks * 32 + lq * 8) << 1;
      af[mt] = *(bf16x8*)((char*)sBuf + m * 256 + (kb ^ ((m & 7) << 4)));
    }
    const int kg = ks * 32 + lq * 8;
#pragma unroll
    for (int g = 0; g < 3; ++g) {
#pragma unroll
      for (int sub = 0; sub < 2; ++sub) {
        const int n = g * 128 + wn * 32 + sub * 16 + l15;
        const bf16x8 bfr = *(const bf16x8*)(whb + (size_t)n * DDIM + kg);
        if (g == 0) {
          accR[0][sub] = MFMA_B16(af[0], bfr, accR[0][sub]);
          accR[1][sub] = MFMA_B16(af[1], bfr, accR[1][sub]);
        } else if (g == 1) {
          accZ[0][sub] = MFMA_B16(af[0], bfr, accZ[0][sub]);
          accZ[1][sub] = MFMA_B16(af[1], bfr, accZ[1][sub]);
        } else {
          accH[0][sub] = MFMA_B16(af[0], bfr, accH[0][sub]);
          accH[1][sub] = MFMA_B16(af[1], bfr, accH[1][sub]);
        }
      }
    }
  }

  // ---------------- Epilogue: gates, scatter new_mem, classifier mem-part ----------------
  float lpM[8][2];
#pragma unroll
  for (int i = 0; i < 8; ++i) { lpM[i][0] = 0.f; lpM[i][1] = 0.f; }

#pragma unroll
  for (int mt = 0; mt < 2; ++mt) {
#pragma unroll
    for (int sub = 0; sub < 2; ++sub) {
      const int d = wn * 32 + sub * 16 + l15;
      const float cw0 = cls_w[EDIM + d];
      const float cw1 = cls_w[CDIM + EDIM + d];
#pragma unroll
      for (int j = 0; j < 4; ++j) {
        const int m = wm * 32 + mt * 16 + lq * 4 + j;
        const float r = sigf(accR[mt][sub][j]);
        const float z = sigf(accZ[mt][sub][j]);
        const float n = tanhf_fast(accN[mt][sub][j] + r * accH[mt][sub][j]);
        const float pv = mem[(size_t)sIds[m] * DDIM + d];
        const float nv = (1.0f - z) * n + z * pv;
        if (m0 + m < Nrows) omem[(size_t)sIds[m] * DDIM + d] = nv;
        lpM[mt * 4 + j][0] += nv * cw0;
        lpM[mt * 4 + j][1] += nv * cw1;
      }
    }
  }

#pragma unroll
  for (int i = 0; i < 8; ++i) {
#pragma unroll
    for (int c = 0; c < 2; ++c) {
      float v = lpM[i][c];
      v += __shfl_xor(v, 1); v += __shfl_xor(v, 2);
      v += __shfl_xor(v, 4); v += __shfl_xor(v, 8);
      if (l15 == 0) {
        const int m = wm * 32 + (i >> 2) * 16 + lq * 4 + (i & 3);
        atomicAdd(&sLp[m][c], v);
      }
    }
  }
  __syncthreads();

  if (t < 128) {
    const int m = t >> 1, c = t & 1;
    if (m0 + m < Nrows) logits[(size_t)(m0 + m) * 2 + c] = sLp[m][c];
  }
}

extern "C" void kernel_launch(void* const* d_in, const int* in_sizes, int n_in,
                              void* d_out, int out_size, void* d_ws, size_t ws_size,
                              hipStream_t stream) {
  const float* emb   = (const float*)d_in[0];
  const int*   ids   = (const int*)d_in[1];
  const float* mem   = (const float*)d_in[2];
  const float* w_ih  = (const float*)d_in[3];
  const float* w_hh  = (const float*)d_in[4];
  const float* b_ih  = (const float*)d_in[5];
  const float* b_hh  = (const float*)d_in[6];
  const float* cls_w = (const float*)d_in[7];
  const float* cls_b = (const float*)d_in[8];

  const int N    = in_sizes[0] / EDIM;   // 100000
  const int MAXN = in_sizes[2] / DDIM;   // 250000

  float* logits = (float*)d_out;
  float* omem   = (float*)d_out + (size_t)N * 2;
  bf16*  wib    = (bf16*)d_ws;
  bf16*  whb    = wib + 3 * DDIM * EDIM;

  // 1) blanket copy memory -> out (stream-ordered; scatter below overwrites node rows)
  hipMemcpyAsync(omem, mem, (size_t)MAXN * DDIM * sizeof(float),
                 hipMemcpyDeviceToDevice, stream);
  // 2) weights to bf16
  const int prep_threads = (3 * DDIM * EDIM + 3 * DDIM * DDIM) / 4;  // 159744
  prep_convert<<<(prep_threads + 255) / 256, 256, 0, stream>>>(w_ih, w_hh, wib, whb);
  // 3) fused GRU + classifier
  gru_fused<<<(N + TM - 1) / TM, 512, 0, stream>>>(emb, ids, mem, b_ih, b_hh,
                                                   cls_w, cls_b, wib, whb,
                                                   logits, omem, N);
}

// Round 3
// 711.354 us; speedup vs baseline: 1.3119x; 1.3119x over previous
//
#include <hip/hip_runtime.h>
#include <hip/hip_bf16.h>

typedef __bf16 bf16;
typedef __bf16 bf16x4 __attribute__((ext_vector_type(4)));
typedef __bf16 bf16x8 __attribute__((ext_vector_type(8)));
typedef float  f32x4  __attribute__((ext_vector_type(4)));

#define EDIM 1536
#define DDIM 128
#define CDIM 1664   // E + D
#define TM   32
#define NSTG 24     // 1536 / 64

#define MFMA_B16(a, b, c) __builtin_amdgcn_mfma_f32_16x16x32_bf16((a), (b), (c), 0, 0, 0)

__device__ __forceinline__ float sigf(float x) { return 1.0f / (1.0f + __expf(-x)); }
__device__ __forceinline__ float tanhf_fast(float x) { return 2.0f / (1.0f + __expf(-2.0f * x)) - 1.0f; }

// f32 -> bf16 weight conversion into workspace
__global__ __launch_bounds__(256) void prep_convert(const float* __restrict__ w_ih,
                                                    const float* __restrict__ w_hh,
                                                    bf16* __restrict__ wib,
                                                    bf16* __restrict__ whb) {
  const int i = (blockIdx.x * 256 + threadIdx.x) * 4;
  const int TIH = 3 * DDIM * EDIM;
  const int THH = 3 * DDIM * DDIM;
  if (i < TIH) {
    const float4 v = *(const float4*)(w_ih + i);
    bf16x4 o = {(bf16)v.x, (bf16)v.y, (bf16)v.z, (bf16)v.w};
    *(bf16x4*)(wib + i) = o;
  } else if (i < TIH + THH) {
    const int j = i - TIH;
    const float4 v = *(const float4*)(w_hh + j);
    bf16x4 o = {(bf16)v.x, (bf16)v.y, (bf16)v.z, (bf16)v.w};
    *(bf16x4*)(whb + j) = o;
  }
}

// TM=32 rows per block, 256 thr = 4 waves. Wave wn owns cols d in [32*wn,+32)
// of each gate; rows split as mt*16 inside the wave. Small blocks -> 3-4
// resident blocks/CU so barriers don't idle the CU (R1 ran 1 block/CU).
__global__ __launch_bounds__(256, 4) void gru_fused(
    const float* __restrict__ emb, const int* __restrict__ ids,
    const float* __restrict__ mem,
    const float* __restrict__ b_ih, const float* __restrict__ b_hh,
    const float* __restrict__ cls_w, const float* __restrict__ cls_b,
    const bf16* __restrict__ wib, const bf16* __restrict__ whb,
    float* __restrict__ logits, float* __restrict__ omem, int Nrows)
{
  __shared__ bf16  sBuf[4096];   // 8KB: phase A dbuf 2 x [32][64] ; phase B [32][128]
  __shared__ float sLp[32][2];
  __shared__ int   sIds[32];

  const int t    = threadIdx.x;
  const int lane = t & 63;
  const int wn   = t >> 6;        // wave index = column group 0..3
  const int l15  = lane & 15;
  const int lq   = lane >> 4;     // 0..3
  const int m0   = blockIdx.x * TM;

  if (t < 32) sIds[t] = (m0 + t < Nrows) ? ids[m0 + t] : 0;
  if (t < 64) sLp[t >> 1][t & 1] = cls_b[t & 1];

  // accumulators, bias-initialized (r,z get b_ih+b_hh; n-gate split: accN=b_ih, accH=b_hh)
  f32x4 accR[2][2], accZ[2][2], accN[2][2], accH[2][2];
#pragma unroll
  for (int sub = 0; sub < 2; ++sub) {
    const int nc = wn * 32 + sub * 16 + l15;
    const float br = b_ih[nc] + b_hh[nc];
    const float bz = b_ih[128 + nc] + b_hh[128 + nc];
    const float bn = b_ih[256 + nc];
    const float bh = b_hh[256 + nc];
#pragma unroll
    for (int mt = 0; mt < 2; ++mt) {
      accR[mt][sub] = (f32x4){br, br, br, br};
      accZ[mt][sub] = (f32x4){bz, bz, bz, bz};
      accN[mt][sub] = (f32x4){bn, bn, bn, bn};
      accH[mt][sub] = (f32x4){bh, bh, bh, bh};
    }
  }

  // ---------------- Phase A: gi over K=1536, BK=64, LDS double-buffered ----------------
  const int srow = t >> 4;            // 0..15
  const int scol = (t & 15) << 2;     // f32 col within 64-wide k-slice
  const bool v0 = (m0 + srow) < Nrows;
  const bool v1 = (m0 + 16 + srow) < Nrows;
  const float* pA0 = emb + (size_t)(m0 + srow) * EDIM + scol;
  const float* pA1 = emb + (size_t)(m0 + 16 + srow) * EDIM + scol;
  const int wb0 = srow * 128        + ((scol << 1) ^ ((srow & 7) << 4));
  const int wb1 = (16 + srow) * 128 + ((scol << 1) ^ ((srow & 7) << 4));
  char* sB0 = (char*)sBuf;
  char* sB1 = (char*)(sBuf + 2048);

  float lpA[2][2] = {{0.f, 0.f}, {0.f, 0.f}};

  { // prologue: stage k-slice 0 into buffer 0
    float4 a0 = make_float4(0.f, 0.f, 0.f, 0.f), a1 = a0;
    if (v0) a0 = *(const float4*)(pA0);
    if (v1) a1 = *(const float4*)(pA1);
    const float4 c0 = *(const float4*)(cls_w + scol);
    const float4 c1 = *(const float4*)(cls_w + CDIM + scol);
    lpA[0][0] += a0.x * c0.x + a0.y * c0.y + a0.z * c0.z + a0.w * c0.w;
    lpA[0][1] += a0.x * c1.x + a0.y * c1.y + a0.z * c1.z + a0.w * c1.w;
    lpA[1][0] += a1.x * c0.x + a1.y * c0.y + a1.z * c0.z + a1.w * c0.w;
    lpA[1][1] += a1.x * c1.x + a1.y * c1.y + a1.z * c1.z + a1.w * c1.w;
    bf16x4 o0 = {(bf16)a0.x, (bf16)a0.y, (bf16)a0.z, (bf16)a0.w};
    bf16x4 o1 = {(bf16)a1.x, (bf16)a1.y, (bf16)a1.z, (bf16)a1.w};
    *(bf16x4*)(sB0 + wb0) = o0;
    *(bf16x4*)(sB0 + wb1) = o1;
  }
  __syncthreads();

  for (int s = 0; s < NSTG; ++s) {
    char* cur = (s & 1) ? sB1 : sB0;
    char* nxt = (s & 1) ? sB0 : sB1;
    const int k0 = s * 64;
    const bool pf = (s + 1) < NSTG;
    float4 a0 = make_float4(0.f, 0.f, 0.f, 0.f), a1 = a0, c0 = a0, c1 = a0;
    if (pf) { // issue next-slice loads early (overlap with MFMA below)
      const int kn = k0 + 64;
      if (v0) a0 = *(const float4*)(pA0 + kn);
      if (v1) a1 = *(const float4*)(pA1 + kn);
      c0 = *(const float4*)(cls_w + kn + scol);
      c1 = *(const float4*)(cls_w + CDIM + kn + scol);
    }
#pragma unroll
    for (int ks = 0; ks < 2; ++ks) {
      bf16x8 af[2];
#pragma unroll
      for (int mt = 0; mt < 2; ++mt) {
        const int m = mt * 16 + l15;
        const int kb = (ks * 32 + lq * 8) << 1;
        af[mt] = *(bf16x8*)(cur + m * 128 + (kb ^ ((m & 7) << 4)));
      }
      const int kg = k0 + ks * 32 + lq * 8;
#pragma unroll
      for (int g = 0; g < 3; ++g) {
#pragma unroll
        for (int sub = 0; sub < 2; ++sub) {
          const int n = g * 128 + wn * 32 + sub * 16 + l15;
          const bf16x8 bfr = *(const bf16x8*)(wib + n * EDIM + kg);
          if (g == 0) {
            accR[0][sub] = MFMA_B16(af[0], bfr, accR[0][sub]);
            accR[1][sub] = MFMA_B16(af[1], bfr, accR[1][sub]);
          } else if (g == 1) {
            accZ[0][sub] = MFMA_B16(af[0], bfr, accZ[0][sub]);
            accZ[1][sub] = MFMA_B16(af[1], bfr, accZ[1][sub]);
          } else {
            accN[0][sub] = MFMA_B16(af[0], bfr, accN[0][sub]);
            accN[1][sub] = MFMA_B16(af[1], bfr, accN[1][sub]);
          }
        }
      }
    }
    if (pf) {
      lpA[0][0] += a0.x * c0.x + a0.y * c0.y + a0.z * c0.z + a0.w * c0.w;
      lpA[0][1] += a0.x * c1.x + a0.y * c1.y + a0.z * c1.z + a0.w * c1.w;
      lpA[1][0] += a1.x * c0.x + a1.y * c0.y + a1.z * c0.z + a1.w * c0.w;
      lpA[1][1] += a1.x * c1.x + a1.y * c1.y + a1.z * c1.z + a1.w * c1.w;
      bf16x4 o0 = {(bf16)a0.x, (bf16)a0.y, (bf16)a0.z, (bf16)a0.w};
      bf16x4 o1 = {(bf16)a1.x, (bf16)a1.y, (bf16)a1.z, (bf16)a1.w};
      *(bf16x4*)(nxt + wb0) = o0;
      *(bf16x4*)(nxt + wb1) = o1;
    }
    __syncthreads();
  }

  // classifier emb-part: reduce over the 16 threads sharing each row -> LDS
#pragma unroll
  for (int p = 0; p < 2; ++p) {
#pragma unroll
    for (int c = 0; c < 2; ++c) {
      float v = lpA[p][c];
      v += __shfl_xor(v, 1); v += __shfl_xor(v, 2);
      v += __shfl_xor(v, 4); v += __shfl_xor(v, 8);
      if (l15 == 0) atomicAdd(&sLp[p * 16 + srow][c], v);
    }
  }

  // ---------------- Phase B: gh over K=128, prev gathered by ids ----------------
  {
    const int prow = t >> 5;            // 0..7
    const int pc   = t & 31;            // f32 quad: col = pc*4
#pragma unroll
    for (int p = 0; p < 4; ++p) {
      const int r = p * 8 + prow;
      const float4 v = *(const float4*)(mem + (size_t)sIds[r] * DDIM + pc * 4);
      bf16x4 o = {(bf16)v.x, (bf16)v.y, (bf16)v.z, (bf16)v.w};
      *(bf16x4*)((char*)sBuf + r * 256 + ((pc << 3) ^ ((r & 7) << 4))) = o;
    }
  }
  __syncthreads();

#pragma unroll
  for (int ks = 0; ks < 4; ++ks) {
    bf16x8 af[2];
#pragma unroll
    for (int mt = 0; mt < 2; ++mt) {
      const int m = mt * 16 + l15;
      const int kb = (ks * 32 + lq * 8) << 1;
      af[mt] = *(bf16x8*)((char*)sBuf + m * 256 + (kb ^ ((m & 7) << 4)));
    }
    const int kg = ks * 32 + lq * 8;
#pragma unroll
    for (int g = 0; g < 3; ++g) {
#pragma unroll
      for (int sub = 0; sub < 2; ++sub) {
        const int n = g * 128 + wn * 32 + sub * 16 + l15;
        const bf16x8 bfr = *(const bf16x8*)(whb + n * DDIM + kg);
        if (g == 0) {
          accR[0][sub] = MFMA_B16(af[0], bfr, accR[0][sub]);
          accR[1][sub] = MFMA_B16(af[1], bfr, accR[1][sub]);
        } else if (g == 1) {
          accZ[0][sub] = MFMA_B16(af[0], bfr, accZ[0][sub]);
          accZ[1][sub] = MFMA_B16(af[1], bfr, accZ[1][sub]);
        } else {
          accH[0][sub] = MFMA_B16(af[0], bfr, accH[0][sub]);
          accH[1][sub] = MFMA_B16(af[1], bfr, accH[1][sub]);
        }
      }
    }
  }

  // ---------------- Epilogue: gates, scatter new_mem, classifier mem-part ----------------
  float lpM[8][2];
#pragma unroll
  for (int i = 0; i < 8; ++i) { lpM[i][0] = 0.f; lpM[i][1] = 0.f; }

#pragma unroll
  for (int mt = 0; mt < 2; ++mt) {
#pragma unroll
    for (int sub = 0; sub < 2; ++sub) {
      const int d = wn * 32 + sub * 16 + l15;
      const float cw0 = cls_w[EDIM + d];
      const float cw1 = cls_w[CDIM + EDIM + d];
#pragma unroll
      for (int j = 0; j < 4; ++j) {
        const int m = mt * 16 + lq * 4 + j;
        const float r = sigf(accR[mt][sub][j]);
        const float z = sigf(accZ[mt][sub][j]);
        const float n = tanhf_fast(accN[mt][sub][j] + r * accH[mt][sub][j]);
        const float pv = mem[(size_t)sIds[m] * DDIM + d];
        const float nv = (1.0f - z) * n + z * pv;
        if (m0 + m < Nrows) omem[(size_t)sIds[m] * DDIM + d] = nv;
        lpM[mt * 4 + j][0] += nv * cw0;
        lpM[mt * 4 + j][1] += nv * cw1;
      }
    }
  }

#pragma unroll
  for (int i = 0; i < 8; ++i) {
#pragma unroll
    for (int c = 0; c < 2; ++c) {
      float v = lpM[i][c];
      v += __shfl_xor(v, 1); v += __shfl_xor(v, 2);
      v += __shfl_xor(v, 4); v += __shfl_xor(v, 8);
      if (l15 == 0) {
        const int m = (i >> 2) * 16 + lq * 4 + (i & 3);
        atomicAdd(&sLp[m][c], v);
      }
    }
  }
  __syncthreads();

  if (t < 64) {
    const int m = t >> 1, c = t & 1;
    if (m0 + m < Nrows) logits[(size_t)(m0 + m) * 2 + c] = sLp[m][c];
  }
}

extern "C" void kernel_launch(void* const* d_in, const int* in_sizes, int n_in,
                              void* d_out, int out_size, void* d_ws, size_t ws_size,
                              hipStream_t stream) {
  const float* emb   = (const float*)d_in[0];
  const int*   ids   = (const int*)d_in[1];
  const float* mem   = (const float*)d_in[2];
  const float* w_ih  = (const float*)d_in[3];
  const float* w_hh  = (const float*)d_in[4];
  const float* b_ih  = (const float*)d_in[5];
  const float* b_hh  = (const float*)d_in[6];
  const float* cls_w = (const float*)d_in[7];
  const float* cls_b = (const float*)d_in[8];

  const int N    = in_sizes[0] / EDIM;   // 100000
  const int MAXN = in_sizes[2] / DDIM;   // 250000

  float* logits = (float*)d_out;
  float* omem   = (float*)d_out + (size_t)N * 2;
  bf16*  wib    = (bf16*)d_ws;
  bf16*  whb    = wib + 3 * DDIM * EDIM;

  // 1) blanket copy memory -> out (stream-ordered; scatter below overwrites node rows)
  hipMemcpyAsync(omem, mem, (size_t)MAXN * DDIM * sizeof(float),
                 hipMemcpyDeviceToDevice, stream);
  // 2) weights to bf16
  const int prep_threads = (3 * DDIM * EDIM + 3 * DDIM * DDIM) / 4;
  prep_convert<<<(prep_threads + 255) / 256, 256, 0, stream>>>(w_ih, w_hh, wib, whb);
  // 3) fused GRU + classifier
  gru_fused<<<(N + TM - 1) / TM, 256, 0, stream>>>(emb, ids, mem, b_ih, b_hh,
                                                   cls_w, cls_b, wib, whb,
                                                   logits, omem, N);
}

// Round 4
// 421.488 us; speedup vs baseline: 2.2142x; 1.6877x over previous
//
#include <hip/hip_runtime.h>
#include <hip/hip_bf16.h>

typedef __bf16 bf16;
typedef __bf16 bf16x4 __attribute__((ext_vector_type(4)));
typedef __bf16 bf16x8 __attribute__((ext_vector_type(8)));
typedef float  f32x4  __attribute__((ext_vector_type(4)));

#define EDIM 1536
#define DDIM 128
#define CDIM 1664   // E + D
#define TM   64
#define NCH  48     // phase A chunks: 1536 / 32

#define MFMA_B16(a, b, c) __builtin_amdgcn_mfma_f32_16x16x32_bf16((a), (b), (c), 0, 0, 0)

__device__ __forceinline__ float sigf(float x) { return 1.0f / (1.0f + __expf(-x)); }
__device__ __forceinline__ float tanhf_fast(float x) { return 2.0f / (1.0f + __expf(-2.0f * x)) - 1.0f; }

__device__ __forceinline__ void glds16(const void* g, void* l) {
  __builtin_amdgcn_global_load_lds(
      (const __attribute__((address_space(1))) unsigned int*)g,
      (__attribute__((address_space(3))) unsigned int*)l, 16, 0, 0);
}

// Stage one 384x32 bf16 weight chunk (24 KB) into LDS, LINEAR layout:
// LDS 16B-seg index s = n*4 + q  holds  w[n][k0 + q*8 .. +8].  No swizzle on
// either side (rule #21 "neither"): glds dest = wave-uniform base + lane*16,
// global source = matching per-lane address. Zero registers held.
template <int LDA>
__device__ __forceinline__ void stageW(const bf16* __restrict__ w, int k0,
                                       char* dst, int wave, int lane) {
#pragma unroll
  for (int j = 0; j < 3; ++j) {
    const int segbase = j * 512 + wave * 64;     // wave-uniform
    const int seg = segbase + lane;              // 0..1535
    const int n = seg >> 2;                      // weight row 0..383
    const int q = seg & 3;                       // 16B-seg within 32-k chunk
    glds16(w + (size_t)n * LDA + k0 + q * 8, dst + (size_t)segbase * 16);
  }
}

// f32 -> bf16 weight conversion into workspace
__global__ __launch_bounds__(256) void prep_convert(const float* __restrict__ w_ih,
                                                    const float* __restrict__ w_hh,
                                                    bf16* __restrict__ wib,
                                                    bf16* __restrict__ whb) {
  const int i = (blockIdx.x * 256 + threadIdx.x) * 4;
  const int TIH = 3 * DDIM * EDIM;
  const int THH = 3 * DDIM * DDIM;
  if (i < TIH) {
    const float4 v = *(const float4*)(w_ih + i);
    bf16x4 o = {(bf16)v.x, (bf16)v.y, (bf16)v.z, (bf16)v.w};
    *(bf16x4*)(wib + i) = o;
  } else if (i < TIH + THH) {
    const int j = i - TIH;
    const float4 v = *(const float4*)(w_hh + j);
    bf16x4 o = {(bf16)v.x, (bf16)v.y, (bf16)v.z, (bf16)v.w};
    *(bf16x4*)(whb + j) = o;
  }
}

// TM=64 rows, 512 thr = 8 waves (wm 0..1 rows, wn 0..3 gate-aligned cols).
// W chunks prefetched into LDS dbuf via global_load_lds (no regs held),
// one barrier per 32-k chunk. 74.8 KB LDS + 128-reg cap -> 2 blocks/CU.
__global__ __launch_bounds__(512, 4) void gru_fused(
    const float* __restrict__ emb, const int* __restrict__ ids,
    const float* __restrict__ mem,
    const float* __restrict__ b_ih, const float* __restrict__ b_hh,
    const float* __restrict__ cls_w, const float* __restrict__ cls_b,
    const bf16* __restrict__ wib, const bf16* __restrict__ whb,
    float* __restrict__ logits, float* __restrict__ omem, int Nrows)
{
  __shared__ char  sW[2][24576];  // W chunk dbuf: 384 rows x 64B (32 k bf16), linear
  __shared__ char  sA[2][5120];   // A slice dbuf: 64 rows x 80B (32 k bf16 + 16B pad)
  __shared__ char  sP[16384];     // prev gathered: 64 rows x 256B (R3-proven swizzle)
  __shared__ float sLp[64][2];
  __shared__ int   sIds[64];

  const int t    = threadIdx.x;
  const int lane = t & 63;
  const int wave = t >> 6;
  const int wm   = wave >> 2;     // 0..1
  const int wn   = wave & 3;      // 0..3
  const int l15  = lane & 15;
  const int lq   = lane >> 4;     // 0..3
  const int m0   = blockIdx.x * TM;

  if (t < 64)  sIds[t] = (m0 + t < Nrows) ? ids[m0 + t] : 0;
  if (t < 128) sLp[t >> 1][t & 1] = cls_b[t & 1];

  // accumulators, bias-initialized (r,z: b_ih+b_hh; n-gate split accN/accH)
  f32x4 accR[2][2], accZ[2][2], accN[2][2], accH[2][2];
#pragma unroll
  for (int sub = 0; sub < 2; ++sub) {
    const int nc = wn * 32 + sub * 16 + l15;
    const float br = b_ih[nc] + b_hh[nc];
    const float bz = b_ih[128 + nc] + b_hh[128 + nc];
    const float bn = b_ih[256 + nc];
    const float bh = b_hh[256 + nc];
#pragma unroll
    for (int mt = 0; mt < 2; ++mt) {
      accR[mt][sub] = (f32x4){br, br, br, br};
      accZ[mt][sub] = (f32x4){bz, bz, bz, bz};
      accN[mt][sub] = (f32x4){bn, bn, bn, bn};
      accH[mt][sub] = (f32x4){bh, bh, bh, bh};
    }
  }

  // A staging role: thread t handles row ar = t>>3, f32-quad aq = t&7
  const int  ar = t >> 3;
  const int  aq = t & 7;
  const bool av = (m0 + ar) < Nrows;
  const float* pA = emb + (size_t)(m0 + ar) * EDIM + aq * 4;
  const int  awofs = ar * 80 + aq * 8;   // bf16x4 (8B) dest within A slice
  float lp0 = 0.f, lp1 = 0.f;

  // ---- prologue: stage chunk 0 (W via glds, A via reg+cvt) ----
  stageW<EDIM>(wib, 0, sW[0], wave, lane);
  {
    float4 a = make_float4(0.f, 0.f, 0.f, 0.f);
    if (av) a = *(const float4*)pA;
    const float4 c0 = *(const float4*)(cls_w + aq * 4);
    const float4 c1 = *(const float4*)(cls_w + CDIM + aq * 4);
    lp0 += a.x * c0.x + a.y * c0.y + a.z * c0.z + a.w * c0.w;
    lp1 += a.x * c1.x + a.y * c1.y + a.z * c1.z + a.w * c1.w;
    bf16x4 o = {(bf16)a.x, (bf16)a.y, (bf16)a.z, (bf16)a.w};
    *(bf16x4*)(sA[0] + awofs) = o;
  }
  __syncthreads();

  // ---- Phase A: gi over K=1536 in 48 chunks of 32, dbuf, 1 barrier/chunk ----
  for (int s = 0; s < NCH; ++s) {
    const int cur = s & 1, nxt = cur ^ 1;
    const bool pf = (s + 1) < NCH;
    if (pf) stageW<EDIM>(wib, (s + 1) * 32, sW[nxt], wave, lane);  // 0-reg prefetch

    bf16x8 af[2];
#pragma unroll
    for (int mt = 0; mt < 2; ++mt) {
      const int m = wm * 32 + mt * 16 + l15;
      af[mt] = *(bf16x8*)(sA[cur] + m * 80 + lq * 16);
    }
#pragma unroll
    for (int g = 0; g < 3; ++g) {
#pragma unroll
      for (int sub = 0; sub < 2; ++sub) {
        const int n = g * 128 + wn * 32 + sub * 16 + l15;
        const bf16x8 bfr = *(bf16x8*)(sW[cur] + n * 64 + lq * 16);
        if (g == 0) {
          accR[0][sub] = MFMA_B16(af[0], bfr, accR[0][sub]);
          accR[1][sub] = MFMA_B16(af[1], bfr, accR[1][sub]);
        } else if (g == 1) {
          accZ[0][sub] = MFMA_B16(af[0], bfr, accZ[0][sub]);
          accZ[1][sub] = MFMA_B16(af[1], bfr, accZ[1][sub]);
        } else {
          accN[0][sub] = MFMA_B16(af[0], bfr, accN[0][sub]);
          accN[1][sub] = MFMA_B16(af[1], bfr, accN[1][sub]);
        }
      }
    }
    if (pf) {  // stage next A slice (+ classifier emb-dot piggyback)
      const int kn = (s + 1) * 32;
      float4 a = make_float4(0.f, 0.f, 0.f, 0.f);
      if (av) a = *(const float4*)(pA + kn);
      const float4 c0 = *(const float4*)(cls_w + kn + aq * 4);
      const float4 c1 = *(const float4*)(cls_w + CDIM + kn + aq * 4);
      lp0 += a.x * c0.x + a.y * c0.y + a.z * c0.z + a.w * c0.w;
      lp1 += a.x * c1.x + a.y * c1.y + a.z * c1.z + a.w * c1.w;
      bf16x4 o = {(bf16)a.x, (bf16)a.y, (bf16)a.z, (bf16)a.w};
      *(bf16x4*)(sA[nxt] + awofs) = o;
    }
    __syncthreads();
  }

  // classifier emb-part: reduce over the 8 threads sharing row ar
  {
    float v0 = lp0, v1 = lp1;
    v0 += __shfl_xor(v0, 1); v0 += __shfl_xor(v0, 2); v0 += __shfl_xor(v0, 4);
    v1 += __shfl_xor(v1, 1); v1 += __shfl_xor(v1, 2); v1 += __shfl_xor(v1, 4);
    if ((lane & 7) == 0) {
      atomicAdd(&sLp[ar][0], v0);
      atomicAdd(&sLp[ar][1], v1);
    }
  }

  // ---- Phase B: gather prev -> sP (R3-proven layout), gh over K=128 ----
  stageW<DDIM>(whb, 0, sW[0], wave, lane);   // phase-A last read was sW[1]
  {
    const int prow = t >> 5;            // 0..15
    const int pc   = t & 31;            // f32 quad: col = pc*4
#pragma unroll
    for (int p = 0; p < 4; ++p) {
      const int r = p * 16 + prow;
      const float4 v = *(const float4*)(mem + (size_t)sIds[r] * DDIM + pc * 4);
      bf16x4 o = {(bf16)v.x, (bf16)v.y, (bf16)v.z, (bf16)v.w};
      *(bf16x4*)(sP + r * 256 + ((pc << 3) ^ ((r & 7) << 4))) = o;
    }
  }
  __syncthreads();

  for (int ks = 0; ks < 4; ++ks) {
    const int cur = ks & 1, nxt = cur ^ 1;
    if (ks + 1 < 4) stageW<DDIM>(whb, (ks + 1) * 32, sW[nxt], wave, lane);
    bf16x8 af[2];
#pragma unroll
    for (int mt = 0; mt < 2; ++mt) {
      const int m = wm * 32 + mt * 16 + l15;
      const int kb = (ks * 32 + lq * 8) << 1;
      af[mt] = *(bf16x8*)(sP + m * 256 + (kb ^ ((m & 7) << 4)));
    }
#pragma unroll
    for (int g = 0; g < 3; ++g) {
#pragma unroll
      for (int sub = 0; sub < 2; ++sub) {
        const int n = g * 128 + wn * 32 + sub * 16 + l15;
        const bf16x8 bfr = *(bf16x8*)(sW[cur] + n * 64 + lq * 16);
        if (g == 0) {
          accR[0][sub] = MFMA_B16(af[0], bfr, accR[0][sub]);
          accR[1][sub] = MFMA_B16(af[1], bfr, accR[1][sub]);
        } else if (g == 1) {
          accZ[0][sub] = MFMA_B16(af[0], bfr, accZ[0][sub]);
          accZ[1][sub] = MFMA_B16(af[1], bfr, accZ[1][sub]);
        } else {
          accH[0][sub] = MFMA_B16(af[0], bfr, accH[0][sub]);
          accH[1][sub] = MFMA_B16(af[1], bfr, accH[1][sub]);
        }
      }
    }
    __syncthreads();
  }

  // ---- Epilogue: gates, scatter new_mem, classifier mem-part ----
  float lpM[8][2];
#pragma unroll
  for (int i = 0; i < 8; ++i) { lpM[i][0] = 0.f; lpM[i][1] = 0.f; }

#pragma unroll
  for (int mt = 0; mt < 2; ++mt) {
#pragma unroll
    for (int sub = 0; sub < 2; ++sub) {
      const int d = wn * 32 + sub * 16 + l15;
      const float cw0 = cls_w[EDIM + d];
      const float cw1 = cls_w[CDIM + EDIM + d];
#pragma unroll
      for (int j = 0; j < 4; ++j) {
        const int m = wm * 32 + mt * 16 + lq * 4 + j;
        const float r = sigf(accR[mt][sub][j]);
        const float z = sigf(accZ[mt][sub][j]);
        const float n = tanhf_fast(accN[mt][sub][j] + r * accH[mt][sub][j]);
        const float pv = mem[(size_t)sIds[m] * DDIM + d];
        const float nv = (1.0f - z) * n + z * pv;
        if (m0 + m < Nrows) omem[(size_t)sIds[m] * DDIM + d] = nv;
        lpM[mt * 4 + j][0] += nv * cw0;
        lpM[mt * 4 + j][1] += nv * cw1;
      }
    }
  }

#pragma unroll
  for (int i = 0; i < 8; ++i) {
#pragma unroll
    for (int c = 0; c < 2; ++c) {
      float v = lpM[i][c];
      v += __shfl_xor(v, 1); v += __shfl_xor(v, 2);
      v += __shfl_xor(v, 4); v += __shfl_xor(v, 8);
      if (l15 == 0) {
        const int m = wm * 32 + (i >> 2) * 16 + lq * 4 + (i & 3);
        atomicAdd(&sLp[m][c], v);
      }
    }
  }
  __syncthreads();

  if (t < 128) {
    const int m = t >> 1, c = t & 1;
    if (m0 + m < Nrows) logits[(size_t)(m0 + m) * 2 + c] = sLp[m][c];
  }
}

extern "C" void kernel_launch(void* const* d_in, const int* in_sizes, int n_in,
                              void* d_out, int out_size, void* d_ws, size_t ws_size,
                              hipStream_t stream) {
  const float* emb   = (const float*)d_in[0];
  const int*   ids   = (const int*)d_in[1];
  const float* mem   = (const float*)d_in[2];
  const float* w_ih  = (const float*)d_in[3];
  const float* w_hh  = (const float*)d_in[4];
  const float* b_ih  = (const float*)d_in[5];
  const float* b_hh  = (const float*)d_in[6];
  const float* cls_w = (const float*)d_in[7];
  const float* cls_b = (const float*)d_in[8];

  const int N    = in_sizes[0] / EDIM;   // 100000
  const int MAXN = in_sizes[2] / DDIM;   // 250000

  float* logits = (float*)d_out;
  float* omem   = (float*)d_out + (size_t)N * 2;
  bf16*  wib    = (bf16*)d_ws;
  bf16*  whb    = wib + 3 * DDIM * EDIM;

  // 1) blanket copy memory -> out (scatter below overwrites active rows)
  hipMemcpyAsync(omem, mem, (size_t)MAXN * DDIM * sizeof(float),
                 hipMemcpyDeviceToDevice, stream);
  // 2) weights to bf16
  const int prep_threads = (3 * DDIM * EDIM + 3 * DDIM * DDIM) / 4;
  prep_convert<<<(prep_threads + 255) / 256, 256, 0, stream>>>(w_ih, w_hh, wib, whb);
  // 3) fused GRU + classifier
  gru_fused<<<(N + TM - 1) / TM, 512, 0, stream>>>(emb, ids, mem, b_ih, b_hh,
                                                   cls_w, cls_b, wib, whb,
                                                   logits, omem, N);
}